// Round 7
// baseline (4984.995 us; speedup 1.0000x reference)
//
#include <hip/hip_runtime.h>

#define NTIME 30
#define NB 4096

typedef __attribute__((ext_vector_type(8))) short short8;
typedef __attribute__((ext_vector_type(4))) float f32x4;
typedef __attribute__((ext_vector_type(16))) float f32x16;

__device__ __forceinline__ unsigned short f2b(float f) {
    unsigned int u = __float_as_uint(f);
    u = u + 0x7FFFu + ((u >> 16) & 1u);        // RNE to bf16
    return (unsigned short)(u >> 16);
}
__device__ __forceinline__ float b2f(unsigned short s) {
    return __uint_as_float(((unsigned int)s) << 16);
}
__device__ __forceinline__ float sigf(float x)     { return 1.0f / (1.0f + __expf(-x)); }
__device__ __forceinline__ float tanhfast(float x) { return 1.0f - 2.0f / (__expf(2.0f * x) + 1.0f); }
// non-temporal 16B loads: keep L2 for the hi-plane working set
__device__ __forceinline__ short8 ntload8(const unsigned short* p) {
    return __builtin_nontemporal_load((const short8*)p);
}
__device__ __forceinline__ f32x4 ntload4f(const float* p) {
    return __builtin_nontemporal_load((const f32x4*)p);
}

// ---- L1 weight pack: 32x32x16 B-frags, bf16 hi/lo planes.
// B-frag: lane holds B[k = (lane>>5)*8 + j][n = lane&31], j=0..7 (k-slot map cancels vs A).
// out[(((s*16 + w)*4 + g)*2 + plane)*512 + lane*8 + j]; k axis = [x 0..64 | h1 0..512], s<36.
__global__ __launch_bounds__(256) void prep_w32(const float* __restrict__ Wih,
                                                const float* __restrict__ Whh,
                                                unsigned short* __restrict__ out)
{
    int e = blockIdx.x * 256 + threadIdx.x;
    if (e >= 36 * 65536) return;
    int j     = e & 7;
    int lane  = (e >> 3) & 63;
    int plane = (e >> 9) & 1;
    int g     = (e >> 10) & 3;
    int w     = (e >> 12) & 15;
    int s     = e >> 16;
    int n = lane & 31, kh = lane >> 5;
    int unit = w * 32 + n;
    int k = s * 16 + kh * 8 + j;
    int row = g * 512 + unit;
    float v = 0.0f;
    if (k < 64) { if (k < 58) v = Wih[row * 58 + k]; }
    else        { v = Whh[row * 512 + (k - 64)]; }
    unsigned short hi = f2b(v);
    out[e] = plane ? f2b(v - b2f(hi)) : hi;
}

// ---- L2/L3 weight pack: 16x16x32 B-frags (validated layout).
__global__ __launch_bounds__(256) void prep_w16(const float* __restrict__ Wih,
                                                const float* __restrict__ Whh,
                                                unsigned short* __restrict__ out,
                                                int H, int KI, int KIp, int KH, int CG, int KS)
{
    int e = blockIdx.x * 256 + threadIdx.x;
    if (e >= KS * CG * 4096) return;
    int j     = e & 7;
    int lane  = (e >> 3) & 63;
    int plane = (e >> 9) & 1;
    int g     = (e >> 10) & 3;
    int rest  = e >> 12;
    int cg = rest % CG;
    int s  = rest / CG;
    int n = lane & 15, q = lane >> 4;
    int unit = cg * 16 + n;
    int k = s * 32 + q * 8 + j;
    int row = g * H + unit;
    float v = 0.0f;
    if (k < KIp) { if (k < KI) v = Wih[row * KI + k]; }
    else         { v = Whh[row * KH + (k - KIp)]; }
    unsigned short hi = f2b(v);
    out[e] = plane ? f2b(v - b2f(hi)) : hi;
}

// ---- Head weight transposes (o-fastest float4 blocks)
__global__ __launch_bounds__(256) void pack_wt1(const float* __restrict__ Wf1, float4* __restrict__ WT1)
{
    int e = blockIdx.x * 256 + threadIdx.x;
    if (e >= 480 * 1024) return;
    int kc = e >> 10, o = e & 1023;
    float4 v = {0.0f, 0.0f, 0.0f, 0.0f};
    if (o < 960) {
        const float* p = Wf1 + (size_t)o * 1920 + kc * 4;
        v.x = p[0]; v.y = p[1]; v.z = p[2]; v.w = p[3];
    }
    WT1[e] = v;
}
__global__ __launch_bounds__(256) void pack_wt2(const float* __restrict__ Wf2, float4* __restrict__ WT2)
{
    int e = blockIdx.x * 256 + threadIdx.x;
    if (e >= 256 * 512) return;
    int kc = e >> 9, o = e & 511;
    float4 v = {0.0f, 0.0f, 0.0f, 0.0f};
    if (o < 480) {
        int k = kc * 4;
        v.x = (k + 0 < 960) ? Wf2[(size_t)o * 960 + k + 0] : 0.0f;
        v.y = (k + 1 < 960) ? Wf2[(size_t)o * 960 + k + 1] : 0.0f;
        v.z = (k + 2 < 960) ? Wf2[(size_t)o * 960 + k + 2] : 0.0f;
        v.w = (k + 3 < 960) ? Wf2[(size_t)o * 960 + k + 3] : 0.0f;
    }
    WT2[e] = v;
}

// ---- Fused Siamese 3-layer LSTM. 256 WGs x 1024 thr (16 waves, 4/SIMD), 129KB LDS.
// L2-residency plan: hi-planes (L1 2.36MB + L2 1.31MB + L3 0.20MB = 3.87MB) stay cached in
// the 4MB per-XCD L2; L1 lo-plane loads + x loads are NON-TEMPORAL (stream via L3, no L2
// allocate), dbuf stores non-temporal -> weight stream becomes L2-hit instead of 15TB/s L3-bound.
__global__ __launch_bounds__(1024, 4) void lstm3_v2(
    const float* __restrict__ x1, const float* __restrict__ x2,
    const unsigned short* __restrict__ l1w, const unsigned short* __restrict__ l2w,
    const unsigned short* __restrict__ l3w,
    const float* __restrict__ b1, const float* __restrict__ b2, const float* __restrict__ b3,
    float* __restrict__ dbuf)
{
    extern __shared__ unsigned short sm[];
    unsigned short* h1hi = sm;                    // [32][520]
    unsigned short* h1lo = h1hi + 32 * 520;
    unsigned short* h2hi = h1lo + 32 * 520;       // [2][32][136]
    unsigned short* h2lo = h2hi + 2 * 32 * 136;
    unsigned short* h3hi = h2lo + 2 * 32 * 136;   // [2][32][72]
    unsigned short* h3lo = h3hi + 2 * 32 * 72;
    unsigned short* xhi  = h3lo + 2 * 32 * 72;    // [32][72]
    unsigned short* xlo  = xhi  + 32 * 72;

    const int tid  = threadIdx.x;
    const int wv   = tid >> 6;
    const int lane = tid & 63;
    const int wg   = blockIdx.x;
    const int samp0 = wg * 16;

    {
        unsigned int* p = (unsigned int*)sm;
        for (int i = tid; i < 64512 / 2; i += 1024) p[i] = 0u;
    }

    // L1 lane mapping (32x32)
    const int n1 = lane & 31;
    const int kh = lane >> 5;
    const int u1 = wv * 32 + n1;
    // L2/L3 lane mapping (16x16)
    const int n2   = lane & 15;
    const int quad = lane >> 4;
    const int mt2  = wv >> 3, cg2 = wv & 7;
    const int u2   = cg2 * 16 + n2;
    const int row2 = mt2 * 16 + n2;
    const int mt3  = (wv >> 2) & 1, cg3 = wv & 3;
    const int u3   = cg3 * 16 + n2;
    const int row3 = mt3 * 16 + n2;

    float c1[16], c2[4], c3[4];
    #pragma unroll
    for (int r = 0; r < 16; ++r) c1[r] = 0.0f;
    #pragma unroll
    for (int r = 0; r < 4; ++r) { c2[r] = 0.0f; c3[r] = 0.0f; }

    const unsigned short* B1p = l1w + wv * 4096 + lane * 8;
    const unsigned short* B2p = l2w + cg2 * 4096 + lane * 8;
    const unsigned short* B3p = l3w + cg3 * 4096 + lane * 8;

    __syncthreads();

    int cur = 0;
    #pragma unroll 1
    for (int t = 0; t < NTIME; ++t) {
        const bool rev = (t & 1);
        const int nxt = cur ^ 1;

        // stage x_t: rows 0-15 from x1, 16-31 from x2 (layout [B,58,30]); pad K to 64.
        // Non-temporal: scattered 4B reads must not evict the weight working set from L2.
        for (int e = tid; e < 2048; e += 1024) {
            int b = e >> 6, f = e & 63;
            const float* __restrict__ xp = (b < 16) ? x1 : x2;
            float v = (f < 58)
                ? __builtin_nontemporal_load(xp + (samp0 + (b & 15)) * 1740 + f * 30 + t)
                : 0.0f;
            unsigned short hi = f2b(v);
            xhi[b * 72 + f] = hi;
            xlo[b * 72 + f] = f2b(v - b2f(hi));
        }
        __syncthreads();   // A

        // ============ L1: 32x32x16, k = [x 64 | h1 512], 36 ksteps ============
        f32x16 A0, A1, A2, A3;
        {
            float bg0 = b1[u1], bg1 = b1[512 + u1], bg2 = b1[1024 + u1], bg3 = b1[1536 + u1];
            #pragma unroll
            for (int r = 0; r < 16; ++r) { A0[r] = bg0; A1[r] = bg1; A2[r] = bg2; A3[r] = bg3; }
        }
        #pragma unroll 1
        for (int ss = 0; ss < 36; ++ss) {
            int s = rev ? (35 - ss) : ss;
            short8 ahi, alo;
            if (s < 4) {
                int off = s * 16 + kh * 8;
                ahi = *(const short8*)(xhi + n1 * 72 + off);
                alo = *(const short8*)(xlo + n1 * 72 + off);
            } else {
                int off = (s - 4) * 16 + kh * 8;
                ahi = *(const short8*)(h1hi + n1 * 520 + off);
                alo = *(const short8*)(h1lo + n1 * 520 + off);
            }
            const unsigned short* bb = B1p + s * 65536;
            short8 bh0 = *(const short8*)(bb);
            short8 bl0 = ntload8(bb + 512);          // lo-plane: nt, stream via L3
            short8 bh1 = *(const short8*)(bb + 1024);
            short8 bl1 = ntload8(bb + 1536);
            short8 bh2 = *(const short8*)(bb + 2048);
            short8 bl2 = ntload8(bb + 2560);
            short8 bh3 = *(const short8*)(bb + 3072);
            short8 bl3 = ntload8(bb + 3584);
            A0 = __builtin_amdgcn_mfma_f32_32x32x16_bf16(ahi, bh0, A0, 0, 0, 0);
            A1 = __builtin_amdgcn_mfma_f32_32x32x16_bf16(ahi, bh1, A1, 0, 0, 0);
            A2 = __builtin_amdgcn_mfma_f32_32x32x16_bf16(ahi, bh2, A2, 0, 0, 0);
            A3 = __builtin_amdgcn_mfma_f32_32x32x16_bf16(ahi, bh3, A3, 0, 0, 0);
            A0 = __builtin_amdgcn_mfma_f32_32x32x16_bf16(alo, bh0, A0, 0, 0, 0);
            A1 = __builtin_amdgcn_mfma_f32_32x32x16_bf16(alo, bh1, A1, 0, 0, 0);
            A2 = __builtin_amdgcn_mfma_f32_32x32x16_bf16(alo, bh2, A2, 0, 0, 0);
            A3 = __builtin_amdgcn_mfma_f32_32x32x16_bf16(alo, bh3, A3, 0, 0, 0);
            A0 = __builtin_amdgcn_mfma_f32_32x32x16_bf16(ahi, bl0, A0, 0, 0, 0);
            A1 = __builtin_amdgcn_mfma_f32_32x32x16_bf16(ahi, bl1, A1, 0, 0, 0);
            A2 = __builtin_amdgcn_mfma_f32_32x32x16_bf16(ahi, bl2, A2, 0, 0, 0);
            A3 = __builtin_amdgcn_mfma_f32_32x32x16_bf16(ahi, bl3, A3, 0, 0, 0);
        }
        __syncthreads();   // B: all reads of h1(t-1)/x done
        #pragma unroll
        for (int r = 0; r < 16; ++r) {
            float I = sigf(A0[r]);
            float F = sigf(A1[r]);
            float G = tanhfast(A2[r]);
            float O = sigf(A3[r]);
            float c = F * c1[r] + I * G;
            c1[r] = c;
            float h = O * tanhfast(c);
            int row = (r & 3) + 8 * (r >> 2) + 4 * kh;   // verified 32x32 C-map
            unsigned short hh = f2b(h);
            h1hi[row * 520 + u1] = hh;
            h1lo[row * 520 + u1] = f2b(h - b2f(hh));
        }
        __syncthreads();   // C: h1(t) visible

        // ============ L2: 16x16x32, k = [relu(h1) 512 | h2 128], 20 ksteps ============
        f32x4 a20, a21, a22, a23;
        {
            float bg0 = b2[u2], bg1 = b2[128 + u2], bg2 = b2[256 + u2], bg3 = b2[384 + u2];
            a20 = (f32x4){bg0, bg0, bg0, bg0};
            a21 = (f32x4){bg1, bg1, bg1, bg1};
            a22 = (f32x4){bg2, bg2, bg2, bg2};
            a23 = (f32x4){bg3, bg3, bg3, bg3};
        }
        #pragma unroll 1
        for (int ss = 0; ss < 20; ++ss) {
            int s = rev ? (19 - ss) : ss;
            short8 ahi, alo;
            if (s < 16) {
                int off = s * 32 + quad * 8;
                short8 a  = *(const short8*)(h1hi + row2 * 520 + off);
                short8 al = *(const short8*)(h1lo + row2 * 520 + off);
                short8 msk = a >> 15;
                ahi = a & ~msk;
                alo = al & ~msk;
            } else {
                int off = (s - 16) * 32 + quad * 8;
                ahi = *(const short8*)(h2hi + cur * 4352 + row2 * 136 + off);
                alo = *(const short8*)(h2lo + cur * 4352 + row2 * 136 + off);
            }
            const unsigned short* bb = B2p + s * 32768;
            short8 bh0 = *(const short8*)(bb);
            short8 bl0 = *(const short8*)(bb + 512);
            short8 bh1 = *(const short8*)(bb + 1024);
            short8 bl1 = *(const short8*)(bb + 1536);
            short8 bh2 = *(const short8*)(bb + 2048);
            short8 bl2 = *(const short8*)(bb + 2560);
            short8 bh3 = *(const short8*)(bb + 3072);
            short8 bl3 = *(const short8*)(bb + 3584);
            a20 = __builtin_amdgcn_mfma_f32_16x16x32_bf16(ahi, bh0, a20, 0, 0, 0);
            a21 = __builtin_amdgcn_mfma_f32_16x16x32_bf16(ahi, bh1, a21, 0, 0, 0);
            a22 = __builtin_amdgcn_mfma_f32_16x16x32_bf16(ahi, bh2, a22, 0, 0, 0);
            a23 = __builtin_amdgcn_mfma_f32_16x16x32_bf16(ahi, bh3, a23, 0, 0, 0);
            a20 = __builtin_amdgcn_mfma_f32_16x16x32_bf16(alo, bh0, a20, 0, 0, 0);
            a21 = __builtin_amdgcn_mfma_f32_16x16x32_bf16(alo, bh1, a21, 0, 0, 0);
            a22 = __builtin_amdgcn_mfma_f32_16x16x32_bf16(alo, bh2, a22, 0, 0, 0);
            a23 = __builtin_amdgcn_mfma_f32_16x16x32_bf16(alo, bh3, a23, 0, 0, 0);
            a20 = __builtin_amdgcn_mfma_f32_16x16x32_bf16(ahi, bl0, a20, 0, 0, 0);
            a21 = __builtin_amdgcn_mfma_f32_16x16x32_bf16(ahi, bl1, a21, 0, 0, 0);
            a22 = __builtin_amdgcn_mfma_f32_16x16x32_bf16(ahi, bl2, a22, 0, 0, 0);
            a23 = __builtin_amdgcn_mfma_f32_16x16x32_bf16(ahi, bl3, a23, 0, 0, 0);
        }
        #pragma unroll
        for (int r = 0; r < 4; ++r) {
            float I = sigf(a20[r]);
            float F = sigf(a21[r]);
            float G = tanhfast(a22[r]);
            float O = sigf(a23[r]);
            float c = F * c2[r] + I * G;
            c2[r] = c;
            float h = O * tanhfast(c);
            int row = mt2 * 16 + quad * 4 + r;
            unsigned short hh = f2b(h);
            h2hi[nxt * 4352 + row * 136 + u2] = hh;
            h2lo[nxt * 4352 + row * 136 + u2] = f2b(h - b2f(hh));
        }
        __syncthreads();   // D: h2(t) visible

        // ============ L3: 16x16x32, k = [relu(h2) 128 | h3 64], 6 ksteps (waves 0-7) ====
        if (wv < 8) {
            f32x4 a30, a31, a32, a33;
            {
                float bg0 = b3[u3], bg1 = b3[64 + u3], bg2 = b3[128 + u3], bg3 = b3[192 + u3];
                a30 = (f32x4){bg0, bg0, bg0, bg0};
                a31 = (f32x4){bg1, bg1, bg1, bg1};
                a32 = (f32x4){bg2, bg2, bg2, bg2};
                a33 = (f32x4){bg3, bg3, bg3, bg3};
            }
            #pragma unroll 1
            for (int ss = 0; ss < 6; ++ss) {
                int s = rev ? (5 - ss) : ss;
                short8 ahi, alo;
                if (s < 4) {
                    int off = s * 32 + quad * 8;
                    short8 a  = *(const short8*)(h2hi + nxt * 4352 + row3 * 136 + off);
                    short8 al = *(const short8*)(h2lo + nxt * 4352 + row3 * 136 + off);
                    short8 msk = a >> 15;
                    ahi = a & ~msk;
                    alo = al & ~msk;
                } else {
                    int off = (s - 4) * 32 + quad * 8;
                    ahi = *(const short8*)(h3hi + cur * 2304 + row3 * 72 + off);
                    alo = *(const short8*)(h3lo + cur * 2304 + row3 * 72 + off);
                }
                const unsigned short* bb = B3p + s * 16384;
                short8 bh0 = *(const short8*)(bb);
                short8 bl0 = *(const short8*)(bb + 512);
                short8 bh1 = *(const short8*)(bb + 1024);
                short8 bl1 = *(const short8*)(bb + 1536);
                short8 bh2 = *(const short8*)(bb + 2048);
                short8 bl2 = *(const short8*)(bb + 2560);
                short8 bh3 = *(const short8*)(bb + 3072);
                short8 bl3 = *(const short8*)(bb + 3584);
                a30 = __builtin_amdgcn_mfma_f32_16x16x32_bf16(ahi, bh0, a30, 0, 0, 0);
                a31 = __builtin_amdgcn_mfma_f32_16x16x32_bf16(ahi, bh1, a31, 0, 0, 0);
                a32 = __builtin_amdgcn_mfma_f32_16x16x32_bf16(ahi, bh2, a32, 0, 0, 0);
                a33 = __builtin_amdgcn_mfma_f32_16x16x32_bf16(ahi, bh3, a33, 0, 0, 0);
                a30 = __builtin_amdgcn_mfma_f32_16x16x32_bf16(alo, bh0, a30, 0, 0, 0);
                a31 = __builtin_amdgcn_mfma_f32_16x16x32_bf16(alo, bh1, a31, 0, 0, 0);
                a32 = __builtin_amdgcn_mfma_f32_16x16x32_bf16(alo, bh2, a32, 0, 0, 0);
                a33 = __builtin_amdgcn_mfma_f32_16x16x32_bf16(alo, bh3, a33, 0, 0, 0);
                a30 = __builtin_amdgcn_mfma_f32_16x16x32_bf16(ahi, bl0, a30, 0, 0, 0);
                a31 = __builtin_amdgcn_mfma_f32_16x16x32_bf16(ahi, bl1, a31, 0, 0, 0);
                a32 = __builtin_amdgcn_mfma_f32_16x16x32_bf16(ahi, bl2, a32, 0, 0, 0);
                a33 = __builtin_amdgcn_mfma_f32_16x16x32_bf16(ahi, bl3, a33, 0, 0, 0);
            }
            #pragma unroll
            for (int r = 0; r < 4; ++r) {
                float I = sigf(a30[r]);
                float F = sigf(a31[r]);
                float G = tanhfast(a32[r]);
                float O = sigf(a33[r]);
                float c = F * c3[r] + I * G;
                c3[r] = c;
                float h = O * tanhfast(c);
                int row = mt3 * 16 + quad * 4 + r;
                unsigned short hh = f2b(h);
                h3hi[nxt * 2304 + row * 72 + u3] = hh;
                h3lo[nxt * 2304 + row * 72 + u3] = f2b(h - b2f(hh));
            }
        }
        __syncthreads();   // E: h3(t) visible

        // d = |relu(h3_x1) - relu(h3_x2)| -> global (nt store: don't pollute L2)
        {
            int b = tid >> 6, u = tid & 63;
            float ha = b2f(h3hi[nxt * 2304 + b * 72 + u]) + b2f(h3lo[nxt * 2304 + b * 72 + u]);
            float hb = b2f(h3hi[nxt * 2304 + (16 + b) * 72 + u]) + b2f(h3lo[nxt * 2304 + (16 + b) * 72 + u]);
            float d = fabsf(fmaxf(ha, 0.0f) - fmaxf(hb, 0.0f));
            __builtin_nontemporal_store(d, &dbuf[(size_t)(samp0 + b) * 1920 + t * 64 + u]);
        }
        cur = nxt;
    }
}

// ---- FC head v2
__global__ __launch_bounds__(512) void head_v2(
    const float* __restrict__ dg,
    const float4* __restrict__ WT1, const float* __restrict__ bf1,
    const float4* __restrict__ WT2, const float* __restrict__ bf2,
    const float* __restrict__ Wf3, const float* __restrict__ bf3,
    const float* __restrict__ Wf4, const float* __restrict__ bf4,
    float* __restrict__ out)
{
    extern __shared__ float hds[];
    float* ds = hds;                  // [16][1928] during fc1
    float* a1 = hds;                  // [16][1032] overlay after fc1
    float* a2 = a1 + 16 * 1032;       // [16][520]
    float* a3 = a2 + 16 * 520;        // [16][16]

    const int tid = threadIdx.x;
    const int samp0 = blockIdx.x * 16;

    for (int e = tid; e < 16 * 480; e += 512) {
        int b = e / 480, jc = e - b * 480;
        f32x4 v = ntload4f(dg + (size_t)(samp0 + b) * 1920 + jc * 4);
        float* dst = ds + b * 1928 + jc * 4;
        dst[0] = v.x; dst[1] = v.y; dst[2] = v.z; dst[3] = v.w;
    }
    __syncthreads();

    const int w = tid >> 6, lane = tid & 63;
    const int oA = w * 128 + lane, oB = oA + 64;
    float accA[16], accB[16];
    {
        float bA = (oA < 960) ? bf1[oA] : 0.0f;
        float bB = (oB < 960) ? bf1[oB] : 0.0f;
        #pragma unroll
        for (int r = 0; r < 16; ++r) { accA[r] = bA; accB[r] = bB; }
    }
    #pragma unroll 2
    for (int kc = 0; kc < 480; ++kc) {
        float4 wA = WT1[kc * 1024 + oA];
        float4 wB = WT1[kc * 1024 + oB];
        #pragma unroll
        for (int r = 0; r < 16; ++r) {
            float4 d4 = ((const float4*)(ds + r * 1928))[kc];
            accA[r] += d4.x * wA.x + d4.y * wA.y + d4.z * wA.z + d4.w * wA.w;
            accB[r] += d4.x * wB.x + d4.y * wB.y + d4.z * wB.z + d4.w * wB.w;
        }
    }
    __syncthreads();
    #pragma unroll
    for (int r = 0; r < 16; ++r) {
        a1[r * 1032 + oA] = fmaxf(accA[r], 0.0f);
        a1[r * 1032 + oB] = fmaxf(accB[r], 0.0f);
    }
    __syncthreads();

    const int o2 = tid;
    float acc2[16];
    {
        float b = (o2 < 480) ? bf2[o2] : 0.0f;
        #pragma unroll
        for (int r = 0; r < 16; ++r) acc2[r] = b;
    }
    #pragma unroll 2
    for (int kc = 0; kc < 256; ++kc) {
        float4 w4 = WT2[kc * 512 + o2];
        #pragma unroll
        for (int r = 0; r < 16; ++r) {
            float4 a4 = ((const float4*)(a1 + r * 1032))[kc];
            acc2[r] += a4.x * w4.x + a4.y * w4.y + a4.z * w4.z + a4.w * w4.w;
        }
    }
    #pragma unroll
    for (int r = 0; r < 16; ++r) a2[r * 520 + o2] = fmaxf(acc2[r], 0.0f);
    __syncthreads();

    if (tid < 256) {
        int o = tid & 15, r = tid >> 4;
        float acc = bf3[o];
        const float4* wr = (const float4*)(Wf3 + (size_t)o * 480);
        const float4* av = (const float4*)(a2 + r * 520);
        #pragma unroll 4
        for (int kc = 0; kc < 120; ++kc) {
            float4 a4 = av[kc];
            float4 w4 = wr[kc];
            acc += a4.x * w4.x + a4.y * w4.y + a4.z * w4.z + a4.w * w4.w;
        }
        a3[r * 16 + o] = fmaxf(acc, 0.0f);
    }
    __syncthreads();

    if (tid < 16) {
        float acc = bf4[0];
        #pragma unroll
        for (int k = 0; k < 16; ++k) acc += a3[tid * 16 + k] * Wf4[k];
        out[samp0 + tid] = acc;
    }
}

extern "C" void kernel_launch(void* const* d_in, const int* in_sizes, int n_in,
                              void* d_out, int out_size, void* d_ws, size_t ws_size,
                              hipStream_t stream) {
    const float* x1   = (const float*)d_in[0];
    const float* x2   = (const float*)d_in[1];
    const float* Wih1 = (const float*)d_in[2];
    const float* Whh1 = (const float*)d_in[3];
    const float* b1   = (const float*)d_in[4];
    const float* Wih2 = (const float*)d_in[5];
    const float* Whh2 = (const float*)d_in[6];
    const float* b2   = (const float*)d_in[7];
    const float* Wih3 = (const float*)d_in[8];
    const float* Whh3 = (const float*)d_in[9];
    const float* b3   = (const float*)d_in[10];
    const float* Wf1  = (const float*)d_in[11];
    const float* bf1  = (const float*)d_in[12];
    const float* Wf2  = (const float*)d_in[13];
    const float* bf2  = (const float*)d_in[14];
    const float* Wf3  = (const float*)d_in[15];
    const float* bf3  = (const float*)d_in[16];
    const float* Wf4  = (const float*)d_in[17];
    const float* bf4  = (const float*)d_in[18];

    float* wsf = (float*)d_ws;
    float* dbuf = wsf;                                         // 4096*1920 = 7,864,320 f32
    unsigned short* l1w = (unsigned short*)(wsf + 7864320);    // 36*65536  = 2,359,296 us
    unsigned short* l2w = l1w + 2359296;                       // 20*8*4096 =   655,360 us
    unsigned short* l3w = l2w + 655360;                        //  6*4*4096 =    98,304 us
    float4* WT1 = (float4*)(wsf + 9420800);                    // 480*1024 float4
    float4* WT2 = WT1 + 480 * 1024;                            // 256*512  float4
    float* out = (float*)d_out;

    prep_w32<<<(36 * 65536) / 256, 256, 0, stream>>>(Wih1, Whh1, l1w);
    prep_w16<<<(20 * 8 * 4096) / 256, 256, 0, stream>>>(Wih2, Whh2, l2w, 128, 512, 512, 128, 8, 20);
    prep_w16<<<(6 * 4 * 4096) / 256, 256, 0, stream>>>(Wih3, Whh3, l3w, 64, 128, 128, 64, 4, 6);
    pack_wt1<<<(480 * 1024) / 256, 256, 0, stream>>>(Wf1, WT1);
    pack_wt2<<<(256 * 512) / 256, 256, 0, stream>>>(Wf2, WT2);

    (void)hipFuncSetAttribute((const void*)lstm3_v2,
                              hipFuncAttributeMaxDynamicSharedMemorySize, 129024);
    lstm3_v2<<<256, 1024, 129024, stream>>>(x1, x2, l1w, l2w, l3w, b1, b2, b3, dbuf);

    (void)hipFuncSetAttribute((const void*)head_v2,
                              hipFuncAttributeMaxDynamicSharedMemorySize, 16 * 1928 * 4);
    head_v2<<<256, 512, 16 * 1928 * 4, stream>>>(dbuf, WT1, bf1, WT2, bf2,
                                                 Wf3, bf3, Wf4, bf4, out);
}

// Round 8
// 4215.612 us; speedup vs baseline: 1.1825x; 1.1825x over previous
//
#include <hip/hip_runtime.h>

#define NTIME 30
#define NB 4096

typedef __attribute__((ext_vector_type(8))) short short8;
typedef __attribute__((ext_vector_type(4))) float f32x4;
typedef __attribute__((ext_vector_type(16))) float f32x16;

__device__ __forceinline__ unsigned short f2b(float f) {
    unsigned int u = __float_as_uint(f);
    u = u + 0x7FFFu + ((u >> 16) & 1u);        // RNE to bf16
    return (unsigned short)(u >> 16);
}
__device__ __forceinline__ float b2f(unsigned short s) {
    return __uint_as_float(((unsigned int)s) << 16);
}
__device__ __forceinline__ float sigf(float x)     { return 1.0f / (1.0f + __expf(-x)); }
__device__ __forceinline__ float tanhfast(float x) { return 1.0f - 2.0f / (__expf(2.0f * x) + 1.0f); }

// ---- L1 weight pack: 32x32x16 B-frags, bf16 hi/lo planes.
// B-frag: lane holds B[k = (lane>>5)*8 + j][n = lane&31], j=0..7 (k-slot map cancels vs A).
// out[(((s*16 + w)*4 + g)*2 + plane)*512 + lane*8 + j]; k axis = [x 0..64 | h1 0..512], s<36.
__global__ __launch_bounds__(256) void prep_w32(const float* __restrict__ Wih,
                                                const float* __restrict__ Whh,
                                                unsigned short* __restrict__ out)
{
    int e = blockIdx.x * 256 + threadIdx.x;
    if (e >= 36 * 65536) return;
    int j     = e & 7;
    int lane  = (e >> 3) & 63;
    int plane = (e >> 9) & 1;
    int g     = (e >> 10) & 3;
    int w     = (e >> 12) & 15;
    int s     = e >> 16;
    int n = lane & 31, kh = lane >> 5;
    int unit = w * 32 + n;
    int k = s * 16 + kh * 8 + j;
    int row = g * 512 + unit;
    float v = 0.0f;
    if (k < 64) { if (k < 58) v = Wih[row * 58 + k]; }
    else        { v = Whh[row * 512 + (k - 64)]; }
    unsigned short hi = f2b(v);
    out[e] = plane ? f2b(v - b2f(hi)) : hi;
}

// ---- L2/L3 weight pack: 16x16x32 B-frags (validated layout).
__global__ __launch_bounds__(256) void prep_w16(const float* __restrict__ Wih,
                                                const float* __restrict__ Whh,
                                                unsigned short* __restrict__ out,
                                                int H, int KI, int KIp, int KH, int CG, int KS)
{
    int e = blockIdx.x * 256 + threadIdx.x;
    if (e >= KS * CG * 4096) return;
    int j     = e & 7;
    int lane  = (e >> 3) & 63;
    int plane = (e >> 9) & 1;
    int g     = (e >> 10) & 3;
    int rest  = e >> 12;
    int cg = rest % CG;
    int s  = rest / CG;
    int n = lane & 15, q = lane >> 4;
    int unit = cg * 16 + n;
    int k = s * 32 + q * 8 + j;
    int row = g * H + unit;
    float v = 0.0f;
    if (k < KIp) { if (k < KI) v = Wih[row * KI + k]; }
    else         { v = Whh[row * KH + (k - KIp)]; }
    unsigned short hi = f2b(v);
    out[e] = plane ? f2b(v - b2f(hi)) : hi;
}

// ---- Head weight transposes (o-fastest float4 blocks)
__global__ __launch_bounds__(256) void pack_wt1(const float* __restrict__ Wf1, float4* __restrict__ WT1)
{
    int e = blockIdx.x * 256 + threadIdx.x;
    if (e >= 480 * 1024) return;
    int kc = e >> 10, o = e & 1023;
    float4 v = {0.0f, 0.0f, 0.0f, 0.0f};
    if (o < 960) {
        const float* p = Wf1 + (size_t)o * 1920 + kc * 4;
        v.x = p[0]; v.y = p[1]; v.z = p[2]; v.w = p[3];
    }
    WT1[e] = v;
}
__global__ __launch_bounds__(256) void pack_wt2(const float* __restrict__ Wf2, float4* __restrict__ WT2)
{
    int e = blockIdx.x * 256 + threadIdx.x;
    if (e >= 256 * 512) return;
    int kc = e >> 9, o = e & 511;
    float4 v = {0.0f, 0.0f, 0.0f, 0.0f};
    if (o < 480) {
        int k = kc * 4;
        v.x = (k + 0 < 960) ? Wf2[(size_t)o * 960 + k + 0] : 0.0f;
        v.y = (k + 1 < 960) ? Wf2[(size_t)o * 960 + k + 1] : 0.0f;
        v.z = (k + 2 < 960) ? Wf2[(size_t)o * 960 + k + 2] : 0.0f;
        v.w = (k + 3 < 960) ? Wf2[(size_t)o * 960 + k + 3] : 0.0f;
    }
    WT2[e] = v;
}

// ---- Fused Siamese 3-layer LSTM. 256 WGs x 1024 thr (16 waves, 4/SIMD), 135KB LDS.
// Round-8: nt hints reverted (r7 regression: L2 is a 32-CU/XCD bandwidth amplifier for the
// shared weight stream — nt defeated it). x_t is double-buffered and prefetched one step
// ahead (overlapped with the L2 k-loop), removing barrier A: 4 barriers/step instead of 5.
__global__ __launch_bounds__(1024, 4) void lstm3_v2(
    const float* __restrict__ x1, const float* __restrict__ x2,
    const unsigned short* __restrict__ l1w, const unsigned short* __restrict__ l2w,
    const unsigned short* __restrict__ l3w,
    const float* __restrict__ b1, const float* __restrict__ b2, const float* __restrict__ b3,
    float* __restrict__ dbuf)
{
    extern __shared__ unsigned short sm[];
    unsigned short* h1hi = sm;                    // [32][520]
    unsigned short* h1lo = h1hi + 32 * 520;
    unsigned short* h2hi = h1lo + 32 * 520;       // [2][32][136]
    unsigned short* h2lo = h2hi + 2 * 32 * 136;
    unsigned short* h3hi = h2lo + 2 * 32 * 136;   // [2][32][72]
    unsigned short* h3lo = h3hi + 2 * 32 * 72;
    unsigned short* xhi  = h3lo + 2 * 32 * 72;    // [2][32][72] double-buffered
    unsigned short* xlo  = xhi  + 2 * 32 * 72;

    const int tid  = threadIdx.x;
    const int wv   = tid >> 6;
    const int lane = tid & 63;
    const int wg   = blockIdx.x;
    const int samp0 = wg * 16;

    // zero recurrent-state LDS (h1/h2/h3 only; x fully overwritten by staging)
    {
        unsigned int* p = (unsigned int*)sm;
        for (int i = tid; i < 29952; i += 1024) p[i] = 0u;
    }

    // L1 lane mapping (32x32)
    const int n1 = lane & 31;
    const int kh = lane >> 5;
    const int u1 = wv * 32 + n1;
    // L2/L3 lane mapping (16x16)
    const int n2   = lane & 15;
    const int quad = lane >> 4;
    const int mt2  = wv >> 3, cg2 = wv & 7;
    const int u2   = cg2 * 16 + n2;
    const int row2 = mt2 * 16 + n2;
    const int mt3  = (wv >> 2) & 1, cg3 = wv & 3;
    const int u3   = cg3 * 16 + n2;
    const int row3 = mt3 * 16 + n2;

    float c1[16], c2[4], c3[4];
    #pragma unroll
    for (int r = 0; r < 16; ++r) c1[r] = 0.0f;
    #pragma unroll
    for (int r = 0; r < 4; ++r) { c2[r] = 0.0f; c3[r] = 0.0f; }

    const unsigned short* B1p = l1w + wv * 4096 + lane * 8;
    const unsigned short* B2p = l2w + cg2 * 4096 + lane * 8;
    const unsigned short* B3p = l3w + cg3 * 4096 + lane * 8;

    // stage x_0 into parity-0 buffer (prologue)
    for (int e = tid; e < 2048; e += 1024) {
        int b = e >> 6, f = e & 63;
        const float* __restrict__ xp = (b < 16) ? x1 : x2;
        float v = (f < 58) ? xp[(samp0 + (b & 15)) * 1740 + f * 30 + 0] : 0.0f;
        unsigned short hi = f2b(v);
        xhi[b * 72 + f] = hi;
        xlo[b * 72 + f] = f2b(v - b2f(hi));
    }
    __syncthreads();

    int cur = 0;
    #pragma unroll 1
    for (int t = 0; t < NTIME; ++t) {
        const bool rev = (t & 1);
        const int nxt = cur ^ 1;
        const unsigned short* xh = xhi + (t & 1) * 2304;
        const unsigned short* xl = xlo + (t & 1) * 2304;

        // ============ L1: 32x32x16, k = [x 64 | h1 512], 36 ksteps ============
        f32x16 A0, A1, A2, A3;
        {
            float bg0 = b1[u1], bg1 = b1[512 + u1], bg2 = b1[1024 + u1], bg3 = b1[1536 + u1];
            #pragma unroll
            for (int r = 0; r < 16; ++r) { A0[r] = bg0; A1[r] = bg1; A2[r] = bg2; A3[r] = bg3; }
        }
        #pragma unroll 1
        for (int ss = 0; ss < 36; ++ss) {
            int s = rev ? (35 - ss) : ss;
            short8 ahi, alo;
            if (s < 4) {
                int off = s * 16 + kh * 8;
                ahi = *(const short8*)(xh + n1 * 72 + off);
                alo = *(const short8*)(xl + n1 * 72 + off);
            } else {
                int off = (s - 4) * 16 + kh * 8;
                ahi = *(const short8*)(h1hi + n1 * 520 + off);
                alo = *(const short8*)(h1lo + n1 * 520 + off);
            }
            const unsigned short* bb = B1p + s * 65536;
            short8 bh0 = *(const short8*)(bb);
            short8 bl0 = *(const short8*)(bb + 512);
            short8 bh1 = *(const short8*)(bb + 1024);
            short8 bl1 = *(const short8*)(bb + 1536);
            short8 bh2 = *(const short8*)(bb + 2048);
            short8 bl2 = *(const short8*)(bb + 2560);
            short8 bh3 = *(const short8*)(bb + 3072);
            short8 bl3 = *(const short8*)(bb + 3584);
            A0 = __builtin_amdgcn_mfma_f32_32x32x16_bf16(ahi, bh0, A0, 0, 0, 0);
            A1 = __builtin_amdgcn_mfma_f32_32x32x16_bf16(ahi, bh1, A1, 0, 0, 0);
            A2 = __builtin_amdgcn_mfma_f32_32x32x16_bf16(ahi, bh2, A2, 0, 0, 0);
            A3 = __builtin_amdgcn_mfma_f32_32x32x16_bf16(ahi, bh3, A3, 0, 0, 0);
            A0 = __builtin_amdgcn_mfma_f32_32x32x16_bf16(alo, bh0, A0, 0, 0, 0);
            A1 = __builtin_amdgcn_mfma_f32_32x32x16_bf16(alo, bh1, A1, 0, 0, 0);
            A2 = __builtin_amdgcn_mfma_f32_32x32x16_bf16(alo, bh2, A2, 0, 0, 0);
            A3 = __builtin_amdgcn_mfma_f32_32x32x16_bf16(alo, bh3, A3, 0, 0, 0);
            A0 = __builtin_amdgcn_mfma_f32_32x32x16_bf16(ahi, bl0, A0, 0, 0, 0);
            A1 = __builtin_amdgcn_mfma_f32_32x32x16_bf16(ahi, bl1, A1, 0, 0, 0);
            A2 = __builtin_amdgcn_mfma_f32_32x32x16_bf16(ahi, bl2, A2, 0, 0, 0);
            A3 = __builtin_amdgcn_mfma_f32_32x32x16_bf16(ahi, bl3, A3, 0, 0, 0);
        }
        __syncthreads();   // B: all reads of h1(t-1)/x(t) done
        #pragma unroll
        for (int r = 0; r < 16; ++r) {
            float I = sigf(A0[r]);
            float F = sigf(A1[r]);
            float G = tanhfast(A2[r]);
            float O = sigf(A3[r]);
            float c = F * c1[r] + I * G;
            c1[r] = c;
            float h = O * tanhfast(c);
            int row = (r & 3) + 8 * (r >> 2) + 4 * kh;   // verified 32x32 C-map
            unsigned short hh = f2b(h);
            h1hi[row * 520 + u1] = hh;
            h1lo[row * 520 + u1] = f2b(h - b2f(hh));
        }
        __syncthreads();   // C: h1(t) visible

        // prefetch x(t+1) into the other parity buffer, overlapped with the L2 k-loop.
        // (writes ordered before next use by barrier D; prior readers of that buffer
        //  finished at barrier B of step t-1)
        if (t + 1 < NTIME) {
            unsigned short* xh2 = xhi + ((t + 1) & 1) * 2304;
            unsigned short* xl2 = xlo + ((t + 1) & 1) * 2304;
            #pragma unroll
            for (int e = tid; e < 2048; e += 1024) {
                int b = e >> 6, f = e & 63;
                const float* __restrict__ xp = (b < 16) ? x1 : x2;
                float v = (f < 58) ? xp[(samp0 + (b & 15)) * 1740 + f * 30 + (t + 1)] : 0.0f;
                unsigned short hi = f2b(v);
                xh2[b * 72 + f] = hi;
                xl2[b * 72 + f] = f2b(v - b2f(hi));
            }
        }

        // ============ L2: 16x16x32, k = [relu(h1) 512 | h2 128], 20 ksteps ============
        f32x4 a20, a21, a22, a23;
        {
            float bg0 = b2[u2], bg1 = b2[128 + u2], bg2 = b2[256 + u2], bg3 = b2[384 + u2];
            a20 = (f32x4){bg0, bg0, bg0, bg0};
            a21 = (f32x4){bg1, bg1, bg1, bg1};
            a22 = (f32x4){bg2, bg2, bg2, bg2};
            a23 = (f32x4){bg3, bg3, bg3, bg3};
        }
        #pragma unroll 1
        for (int ss = 0; ss < 20; ++ss) {
            int s = rev ? (19 - ss) : ss;
            short8 ahi, alo;
            if (s < 16) {
                int off = s * 32 + quad * 8;
                short8 a  = *(const short8*)(h1hi + row2 * 520 + off);
                short8 al = *(const short8*)(h1lo + row2 * 520 + off);
                short8 msk = a >> 15;
                ahi = a & ~msk;
                alo = al & ~msk;
            } else {
                int off = (s - 16) * 32 + quad * 8;
                ahi = *(const short8*)(h2hi + cur * 4352 + row2 * 136 + off);
                alo = *(const short8*)(h2lo + cur * 4352 + row2 * 136 + off);
            }
            const unsigned short* bb = B2p + s * 32768;
            short8 bh0 = *(const short8*)(bb);
            short8 bl0 = *(const short8*)(bb + 512);
            short8 bh1 = *(const short8*)(bb + 1024);
            short8 bl1 = *(const short8*)(bb + 1536);
            short8 bh2 = *(const short8*)(bb + 2048);
            short8 bl2 = *(const short8*)(bb + 2560);
            short8 bh3 = *(const short8*)(bb + 3072);
            short8 bl3 = *(const short8*)(bb + 3584);
            a20 = __builtin_amdgcn_mfma_f32_16x16x32_bf16(ahi, bh0, a20, 0, 0, 0);
            a21 = __builtin_amdgcn_mfma_f32_16x16x32_bf16(ahi, bh1, a21, 0, 0, 0);
            a22 = __builtin_amdgcn_mfma_f32_16x16x32_bf16(ahi, bh2, a22, 0, 0, 0);
            a23 = __builtin_amdgcn_mfma_f32_16x16x32_bf16(ahi, bh3, a23, 0, 0, 0);
            a20 = __builtin_amdgcn_mfma_f32_16x16x32_bf16(alo, bh0, a20, 0, 0, 0);
            a21 = __builtin_amdgcn_mfma_f32_16x16x32_bf16(alo, bh1, a21, 0, 0, 0);
            a22 = __builtin_amdgcn_mfma_f32_16x16x32_bf16(alo, bh2, a22, 0, 0, 0);
            a23 = __builtin_amdgcn_mfma_f32_16x16x32_bf16(alo, bh3, a23, 0, 0, 0);
            a20 = __builtin_amdgcn_mfma_f32_16x16x32_bf16(ahi, bl0, a20, 0, 0, 0);
            a21 = __builtin_amdgcn_mfma_f32_16x16x32_bf16(ahi, bl1, a21, 0, 0, 0);
            a22 = __builtin_amdgcn_mfma_f32_16x16x32_bf16(ahi, bl2, a22, 0, 0, 0);
            a23 = __builtin_amdgcn_mfma_f32_16x16x32_bf16(ahi, bl3, a23, 0, 0, 0);
        }
        #pragma unroll
        for (int r = 0; r < 4; ++r) {
            float I = sigf(a20[r]);
            float F = sigf(a21[r]);
            float G = tanhfast(a22[r]);
            float O = sigf(a23[r]);
            float c = F * c2[r] + I * G;
            c2[r] = c;
            float h = O * tanhfast(c);
            int row = mt2 * 16 + quad * 4 + r;
            unsigned short hh = f2b(h);
            h2hi[nxt * 4352 + row * 136 + u2] = hh;
            h2lo[nxt * 4352 + row * 136 + u2] = f2b(h - b2f(hh));
        }
        __syncthreads();   // D: h2(t) + x(t+1) visible

        // ============ L3: 16x16x32, k = [relu(h2) 128 | h3 64], 6 ksteps (waves 0-7) ====
        if (wv < 8) {
            f32x4 a30, a31, a32, a33;
            {
                float bg0 = b3[u3], bg1 = b3[64 + u3], bg2 = b3[128 + u3], bg3 = b3[192 + u3];
                a30 = (f32x4){bg0, bg0, bg0, bg0};
                a31 = (f32x4){bg1, bg1, bg1, bg1};
                a32 = (f32x4){bg2, bg2, bg2, bg2};
                a33 = (f32x4){bg3, bg3, bg3, bg3};
            }
            #pragma unroll 1
            for (int ss = 0; ss < 6; ++ss) {
                int s = rev ? (5 - ss) : ss;
                short8 ahi, alo;
                if (s < 4) {
                    int off = s * 32 + quad * 8;
                    short8 a  = *(const short8*)(h2hi + nxt * 4352 + row3 * 136 + off);
                    short8 al = *(const short8*)(h2lo + nxt * 4352 + row3 * 136 + off);
                    short8 msk = a >> 15;
                    ahi = a & ~msk;
                    alo = al & ~msk;
                } else {
                    int off = (s - 4) * 32 + quad * 8;
                    ahi = *(const short8*)(h3hi + cur * 2304 + row3 * 72 + off);
                    alo = *(const short8*)(h3lo + cur * 2304 + row3 * 72 + off);
                }
                const unsigned short* bb = B3p + s * 16384;
                short8 bh0 = *(const short8*)(bb);
                short8 bl0 = *(const short8*)(bb + 512);
                short8 bh1 = *(const short8*)(bb + 1024);
                short8 bl1 = *(const short8*)(bb + 1536);
                short8 bh2 = *(const short8*)(bb + 2048);
                short8 bl2 = *(const short8*)(bb + 2560);
                short8 bh3 = *(const short8*)(bb + 3072);
                short8 bl3 = *(const short8*)(bb + 3584);
                a30 = __builtin_amdgcn_mfma_f32_16x16x32_bf16(ahi, bh0, a30, 0, 0, 0);
                a31 = __builtin_amdgcn_mfma_f32_16x16x32_bf16(ahi, bh1, a31, 0, 0, 0);
                a32 = __builtin_amdgcn_mfma_f32_16x16x32_bf16(ahi, bh2, a32, 0, 0, 0);
                a33 = __builtin_amdgcn_mfma_f32_16x16x32_bf16(ahi, bh3, a33, 0, 0, 0);
                a30 = __builtin_amdgcn_mfma_f32_16x16x32_bf16(alo, bh0, a30, 0, 0, 0);
                a31 = __builtin_amdgcn_mfma_f32_16x16x32_bf16(alo, bh1, a31, 0, 0, 0);
                a32 = __builtin_amdgcn_mfma_f32_16x16x32_bf16(alo, bh2, a32, 0, 0, 0);
                a33 = __builtin_amdgcn_mfma_f32_16x16x32_bf16(alo, bh3, a33, 0, 0, 0);
                a30 = __builtin_amdgcn_mfma_f32_16x16x32_bf16(ahi, bl0, a30, 0, 0, 0);
                a31 = __builtin_amdgcn_mfma_f32_16x16x32_bf16(ahi, bl1, a31, 0, 0, 0);
                a32 = __builtin_amdgcn_mfma_f32_16x16x32_bf16(ahi, bl2, a32, 0, 0, 0);
                a33 = __builtin_amdgcn_mfma_f32_16x16x32_bf16(ahi, bl3, a33, 0, 0, 0);
            }
            #pragma unroll
            for (int r = 0; r < 4; ++r) {
                float I = sigf(a30[r]);
                float F = sigf(a31[r]);
                float G = tanhfast(a32[r]);
                float O = sigf(a33[r]);
                float c = F * c3[r] + I * G;
                c3[r] = c;
                float h = O * tanhfast(c);
                int row = mt3 * 16 + quad * 4 + r;
                unsigned short hh = f2b(h);
                h3hi[nxt * 2304 + row * 72 + u3] = hh;
                h3lo[nxt * 2304 + row * 72 + u3] = f2b(h - b2f(hh));
            }
        }
        __syncthreads();   // E: h3(t) visible

        // d = |relu(h3_x1) - relu(h3_x2)| -> global
        {
            int b = tid >> 6, u = tid & 63;
            float ha = b2f(h3hi[nxt * 2304 + b * 72 + u]) + b2f(h3lo[nxt * 2304 + b * 72 + u]);
            float hb = b2f(h3hi[nxt * 2304 + (16 + b) * 72 + u]) + b2f(h3lo[nxt * 2304 + (16 + b) * 72 + u]);
            dbuf[(size_t)(samp0 + b) * 1920 + t * 64 + u] = fabsf(fmaxf(ha, 0.0f) - fmaxf(hb, 0.0f));
        }
        cur = nxt;
    }
}

// ---- FC head v2 (round-5 version, nt removed)
__global__ __launch_bounds__(512) void head_v2(
    const float* __restrict__ dg,
    const float4* __restrict__ WT1, const float* __restrict__ bf1,
    const float4* __restrict__ WT2, const float* __restrict__ bf2,
    const float* __restrict__ Wf3, const float* __restrict__ bf3,
    const float* __restrict__ Wf4, const float* __restrict__ bf4,
    float* __restrict__ out)
{
    extern __shared__ float hds[];
    float* ds = hds;                  // [16][1928] during fc1
    float* a1 = hds;                  // [16][1032] overlay after fc1
    float* a2 = a1 + 16 * 1032;       // [16][520]
    float* a3 = a2 + 16 * 520;        // [16][16]

    const int tid = threadIdx.x;
    const int samp0 = blockIdx.x * 16;

    for (int e = tid; e < 16 * 480; e += 512) {
        int b = e / 480, jc = e - b * 480;
        const float* src = dg + (size_t)(samp0 + b) * 1920 + jc * 4;
        float* dst = ds + b * 1928 + jc * 4;
        dst[0] = src[0]; dst[1] = src[1]; dst[2] = src[2]; dst[3] = src[3];
    }
    __syncthreads();

    const int w = tid >> 6, lane = tid & 63;
    const int oA = w * 128 + lane, oB = oA + 64;
    float accA[16], accB[16];
    {
        float bA = (oA < 960) ? bf1[oA] : 0.0f;
        float bB = (oB < 960) ? bf1[oB] : 0.0f;
        #pragma unroll
        for (int r = 0; r < 16; ++r) { accA[r] = bA; accB[r] = bB; }
    }
    #pragma unroll 2
    for (int kc = 0; kc < 480; ++kc) {
        float4 wA = WT1[kc * 1024 + oA];
        float4 wB = WT1[kc * 1024 + oB];
        #pragma unroll
        for (int r = 0; r < 16; ++r) {
            float4 d4 = ((const float4*)(ds + r * 1928))[kc];
            accA[r] += d4.x * wA.x + d4.y * wA.y + d4.z * wA.z + d4.w * wA.w;
            accB[r] += d4.x * wB.x + d4.y * wB.y + d4.z * wB.z + d4.w * wB.w;
        }
    }
    __syncthreads();
    #pragma unroll
    for (int r = 0; r < 16; ++r) {
        a1[r * 1032 + oA] = fmaxf(accA[r], 0.0f);
        a1[r * 1032 + oB] = fmaxf(accB[r], 0.0f);
    }
    __syncthreads();

    const int o2 = tid;
    float acc2[16];
    {
        float b = (o2 < 480) ? bf2[o2] : 0.0f;
        #pragma unroll
        for (int r = 0; r < 16; ++r) acc2[r] = b;
    }
    #pragma unroll 2
    for (int kc = 0; kc < 256; ++kc) {
        float4 w4 = WT2[kc * 512 + o2];
        #pragma unroll
        for (int r = 0; r < 16; ++r) {
            float4 a4 = ((const float4*)(a1 + r * 1032))[kc];
            acc2[r] += a4.x * w4.x + a4.y * w4.y + a4.z * w4.z + a4.w * w4.w;
        }
    }
    #pragma unroll
    for (int r = 0; r < 16; ++r) a2[r * 520 + o2] = fmaxf(acc2[r], 0.0f);
    __syncthreads();

    if (tid < 256) {
        int o = tid & 15, r = tid >> 4;
        float acc = bf3[o];
        const float4* wr = (const float4*)(Wf3 + (size_t)o * 480);
        const float4* av = (const float4*)(a2 + r * 520);
        #pragma unroll 4
        for (int kc = 0; kc < 120; ++kc) {
            float4 a4 = av[kc];
            float4 w4 = wr[kc];
            acc += a4.x * w4.x + a4.y * w4.y + a4.z * w4.z + a4.w * w4.w;
        }
        a3[r * 16 + o] = fmaxf(acc, 0.0f);
    }
    __syncthreads();

    if (tid < 16) {
        float acc = bf4[0];
        #pragma unroll
        for (int k = 0; k < 16; ++k) acc += a3[tid * 16 + k] * Wf4[k];
        out[samp0 + tid] = acc;
    }
}

extern "C" void kernel_launch(void* const* d_in, const int* in_sizes, int n_in,
                              void* d_out, int out_size, void* d_ws, size_t ws_size,
                              hipStream_t stream) {
    const float* x1   = (const float*)d_in[0];
    const float* x2   = (const float*)d_in[1];
    const float* Wih1 = (const float*)d_in[2];
    const float* Whh1 = (const float*)d_in[3];
    const float* b1   = (const float*)d_in[4];
    const float* Wih2 = (const float*)d_in[5];
    const float* Whh2 = (const float*)d_in[6];
    const float* b2   = (const float*)d_in[7];
    const float* Wih3 = (const float*)d_in[8];
    const float* Whh3 = (const float*)d_in[9];
    const float* b3   = (const float*)d_in[10];
    const float* Wf1  = (const float*)d_in[11];
    const float* bf1  = (const float*)d_in[12];
    const float* Wf2  = (const float*)d_in[13];
    const float* bf2  = (const float*)d_in[14];
    const float* Wf3  = (const float*)d_in[15];
    const float* bf3  = (const float*)d_in[16];
    const float* Wf4  = (const float*)d_in[17];
    const float* bf4  = (const float*)d_in[18];

    float* wsf = (float*)d_ws;
    float* dbuf = wsf;                                         // 4096*1920 = 7,864,320 f32
    unsigned short* l1w = (unsigned short*)(wsf + 7864320);    // 36*65536  = 2,359,296 us
    unsigned short* l2w = l1w + 2359296;                       // 20*8*4096 =   655,360 us
    unsigned short* l3w = l2w + 655360;                        //  6*4*4096 =    98,304 us
    float4* WT1 = (float4*)(wsf + 9420800);                    // 480*1024 float4
    float4* WT2 = WT1 + 480 * 1024;                            // 256*512  float4
    float* out = (float*)d_out;

    prep_w32<<<(36 * 65536) / 256, 256, 0, stream>>>(Wih1, Whh1, l1w);
    prep_w16<<<(20 * 8 * 4096) / 256, 256, 0, stream>>>(Wih2, Whh2, l2w, 128, 512, 512, 128, 8, 20);
    prep_w16<<<(6 * 4 * 4096) / 256, 256, 0, stream>>>(Wih3, Whh3, l3w, 64, 128, 128, 64, 4, 6);
    pack_wt1<<<(480 * 1024) / 256, 256, 0, stream>>>(Wf1, WT1);
    pack_wt2<<<(256 * 512) / 256, 256, 0, stream>>>(Wf2, WT2);

    (void)hipFuncSetAttribute((const void*)lstm3_v2,
                              hipFuncAttributeMaxDynamicSharedMemorySize, 138240);
    lstm3_v2<<<256, 1024, 138240, stream>>>(x1, x2, l1w, l2w, l3w, b1, b2, b3, dbuf);

    (void)hipFuncSetAttribute((const void*)head_v2,
                              hipFuncAttributeMaxDynamicSharedMemorySize, 16 * 1928 * 4);
    head_v2<<<256, 512, 16 * 1928 * 4, stream>>>(dbuf, WT1, bf1, WT2, bf2,
                                                 Wf3, bf3, Wf4, bf4, out);
}

// Round 9
// 3993.294 us; speedup vs baseline: 1.2483x; 1.0557x over previous
//
#include <hip/hip_runtime.h>

#define NTIME 30
#define NB 4096

typedef __attribute__((ext_vector_type(8))) short short8;
typedef __attribute__((ext_vector_type(4))) float f32x4;
typedef __attribute__((ext_vector_type(16))) float f32x16;

__device__ __forceinline__ unsigned short f2b(float f) {
    unsigned int u = __float_as_uint(f);
    u = u + 0x7FFFu + ((u >> 16) & 1u);        // RNE to bf16
    return (unsigned short)(u >> 16);
}
__device__ __forceinline__ float b2f(unsigned short s) {
    return __uint_as_float(((unsigned int)s) << 16);
}
__device__ __forceinline__ float sigf(float x)     { return 1.0f / (1.0f + __expf(-x)); }
__device__ __forceinline__ float tanhfast(float x) { return 1.0f - 2.0f / (__expf(2.0f * x) + 1.0f); }

// ---- L1 weight pack: 32x32x16 B-frags, bf16 hi/lo planes (layout unchanged, validated).
__global__ __launch_bounds__(256) void prep_w32(const float* __restrict__ Wih,
                                                const float* __restrict__ Whh,
                                                unsigned short* __restrict__ out)
{
    int e = blockIdx.x * 256 + threadIdx.x;
    if (e >= 36 * 65536) return;
    int j     = e & 7;
    int lane  = (e >> 3) & 63;
    int plane = (e >> 9) & 1;
    int g     = (e >> 10) & 3;
    int w     = (e >> 12) & 15;
    int s     = e >> 16;
    int n = lane & 31, kh = lane >> 5;
    int unit = w * 32 + n;
    int k = s * 16 + kh * 8 + j;
    int row = g * 512 + unit;
    float v = 0.0f;
    if (k < 64) { if (k < 58) v = Wih[row * 58 + k]; }
    else        { v = Whh[row * 512 + (k - 64)]; }
    unsigned short hi = f2b(v);
    out[e] = plane ? f2b(v - b2f(hi)) : hi;
}

// ---- L2/L3 weight pack: 16x16x32 B-frags (validated layout).
__global__ __launch_bounds__(256) void prep_w16(const float* __restrict__ Wih,
                                                const float* __restrict__ Whh,
                                                unsigned short* __restrict__ out,
                                                int H, int KI, int KIp, int KH, int CG, int KS)
{
    int e = blockIdx.x * 256 + threadIdx.x;
    if (e >= KS * CG * 4096) return;
    int j     = e & 7;
    int lane  = (e >> 3) & 63;
    int plane = (e >> 9) & 1;
    int g     = (e >> 10) & 3;
    int rest  = e >> 12;
    int cg = rest % CG;
    int s  = rest / CG;
    int n = lane & 15, q = lane >> 4;
    int unit = cg * 16 + n;
    int k = s * 32 + q * 8 + j;
    int row = g * H + unit;
    float v = 0.0f;
    if (k < KIp) { if (k < KI) v = Wih[row * KI + k]; }
    else         { v = Whh[row * KH + (k - KIp)]; }
    unsigned short hi = f2b(v);
    out[e] = plane ? f2b(v - b2f(hi)) : hi;
}

// ---- Head weight transposes (o-fastest float4 blocks)
__global__ __launch_bounds__(256) void pack_wt1(const float* __restrict__ Wf1, float4* __restrict__ WT1)
{
    int e = blockIdx.x * 256 + threadIdx.x;
    if (e >= 480 * 1024) return;
    int kc = e >> 10, o = e & 1023;
    float4 v = {0.0f, 0.0f, 0.0f, 0.0f};
    if (o < 960) {
        const float* p = Wf1 + (size_t)o * 1920 + kc * 4;
        v.x = p[0]; v.y = p[1]; v.z = p[2]; v.w = p[3];
    }
    WT1[e] = v;
}
__global__ __launch_bounds__(256) void pack_wt2(const float* __restrict__ Wf2, float4* __restrict__ WT2)
{
    int e = blockIdx.x * 256 + threadIdx.x;
    if (e >= 256 * 512) return;
    int kc = e >> 9, o = e & 511;
    float4 v = {0.0f, 0.0f, 0.0f, 0.0f};
    if (o < 480) {
        int k = kc * 4;
        v.x = (k + 0 < 960) ? Wf2[(size_t)o * 960 + k + 0] : 0.0f;
        v.y = (k + 1 < 960) ? Wf2[(size_t)o * 960 + k + 1] : 0.0f;
        v.z = (k + 2 < 960) ? Wf2[(size_t)o * 960 + k + 2] : 0.0f;
        v.w = (k + 3 < 960) ? Wf2[(size_t)o * 960 + k + 3] : 0.0f;
    }
    WT2[e] = v;
}

#define MFMA32(A, X, B) A = __builtin_amdgcn_mfma_f32_32x32x16_bf16((X), (B), (A), 0, 0, 0)
#define MFMA16(A, X, B) A = __builtin_amdgcn_mfma_f32_16x16x32_bf16((X), (B), (A), 0, 0, 0)

// ---- Fused Siamese 3-layer LSTM. 256 WGs x 1024 thr (16 waves, 4/SIMD), 135KB LDS.
// Round-9: software-pipelined weight stream. L1 runs as TWO gate-pair passes (i,f then g,o;
// cell update folded: c*=F after pass0, c+=I*G after pass1) cutting live acc 64->32 AGPRs,
// freeing VGPRs for a 1-kstep-ahead register prefetch of hi-plane B-frags. L2/L3 k-loops get
// full 8-frag 1-deep prefetch. Targets the exposed per-kstep L2/IC load latency (r8 diagnosis:
// VGPR cap 128 left zero prefetch depth -> ~75% of cycles were bare memory latency).
__global__ __launch_bounds__(1024, 4) void lstm3_v2(
    const float* __restrict__ x1, const float* __restrict__ x2,
    const unsigned short* __restrict__ l1w, const unsigned short* __restrict__ l2w,
    const unsigned short* __restrict__ l3w,
    const float* __restrict__ b1, const float* __restrict__ b2, const float* __restrict__ b3,
    float* __restrict__ dbuf)
{
    extern __shared__ unsigned short sm[];
    unsigned short* h1hi = sm;                    // [32][520]
    unsigned short* h1lo = h1hi + 32 * 520;
    unsigned short* h2hi = h1lo + 32 * 520;       // [2][32][136]
    unsigned short* h2lo = h2hi + 2 * 32 * 136;
    unsigned short* h3hi = h2lo + 2 * 32 * 136;   // [2][32][72]
    unsigned short* h3lo = h3hi + 2 * 32 * 72;
    unsigned short* xhi  = h3lo + 2 * 32 * 72;    // [2][32][72] double-buffered
    unsigned short* xlo  = xhi  + 2 * 32 * 72;

    const int tid  = threadIdx.x;
    const int wv   = tid >> 6;
    const int lane = tid & 63;
    const int wg   = blockIdx.x;
    const int samp0 = wg * 16;

    {
        unsigned int* p = (unsigned int*)sm;
        for (int i = tid; i < 29952; i += 1024) p[i] = 0u;
    }

    // L1 lane mapping (32x32)
    const int n1 = lane & 31;
    const int kh = lane >> 5;
    const int u1 = wv * 32 + n1;
    // L2/L3 lane mapping (16x16)
    const int n2   = lane & 15;
    const int quad = lane >> 4;
    const int mt2  = wv >> 3, cg2 = wv & 7;
    const int u2   = cg2 * 16 + n2;
    const int row2 = mt2 * 16 + n2;
    const int mt3  = (wv >> 2) & 1, cg3 = wv & 3;
    const int u3   = cg3 * 16 + n2;
    const int row3 = mt3 * 16 + n2;

    float c1[16], c2[4], c3[4];
    #pragma unroll
    for (int r = 0; r < 16; ++r) c1[r] = 0.0f;
    #pragma unroll
    for (int r = 0; r < 4; ++r) { c2[r] = 0.0f; c3[r] = 0.0f; }

    const unsigned short* B1p = l1w + wv * 4096 + lane * 8;
    const unsigned short* B2p = l2w + cg2 * 4096 + lane * 8;
    const unsigned short* B3p = l3w + cg3 * 4096 + lane * 8;

    // stage x_0 into parity-0 buffer (prologue)
    for (int e = tid; e < 2048; e += 1024) {
        int b = e >> 6, f = e & 63;
        const float* __restrict__ xp = (b < 16) ? x1 : x2;
        float v = (f < 58) ? xp[(samp0 + (b & 15)) * 1740 + f * 30 + 0] : 0.0f;
        unsigned short hi = f2b(v);
        xhi[b * 72 + f] = hi;
        xlo[b * 72 + f] = f2b(v - b2f(hi));
    }
    __syncthreads();

    int cur = 0;
    #pragma unroll 1
    for (int t = 0; t < NTIME; ++t) {
        const bool rev = (t & 1);
        const int nxt = cur ^ 1;
        const unsigned short* xh = xhi + (t & 1) * 2304;
        const unsigned short* xl = xlo + (t & 1) * 2304;

        float i1[16];   // sigmoid(i-gate), carried from pass 0 to pass 1

        // ============ L1 pass 0: gates i,f; k = [x 64 | h1 512], 36 ksteps ============
        {
            f32x16 P0, P1;
            {
                float bg0 = b1[u1], bg1 = b1[512 + u1];
                #pragma unroll
                for (int r = 0; r < 16; ++r) { P0[r] = bg0; P1[r] = bg1; }
            }
            short8 pb0, pb1;   // hi-frag prefetch, 1 kstep ahead
            {
                int s0 = rev ? 35 : 0;
                const unsigned short* bb = B1p + s0 * 65536;
                pb0 = *(const short8*)(bb);
                pb1 = *(const short8*)(bb + 1024);
            }
            #pragma unroll 1
            for (int ss = 0; ss < 36; ++ss) {
                int s = rev ? (35 - ss) : ss;
                short8 ahi, alo;
                if (s < 4) {
                    int off = s * 16 + kh * 8;
                    ahi = *(const short8*)(xh + n1 * 72 + off);
                    alo = *(const short8*)(xl + n1 * 72 + off);
                } else {
                    int off = (s - 4) * 16 + kh * 8;
                    ahi = *(const short8*)(h1hi + n1 * 520 + off);
                    alo = *(const short8*)(h1lo + n1 * 520 + off);
                }
                const unsigned short* bbc = B1p + s * 65536;
                short8 bl0 = *(const short8*)(bbc + 512);
                short8 bl1 = *(const short8*)(bbc + 1536);
                short8 b0 = pb0, b1c = pb1;
                if (ss + 1 < 36) {
                    int s2 = rev ? (34 - ss) : (ss + 1);
                    const unsigned short* bb2 = B1p + s2 * 65536;
                    pb0 = *(const short8*)(bb2);
                    pb1 = *(const short8*)(bb2 + 1024);
                }
                MFMA32(P0, ahi, b0);
                MFMA32(P1, ahi, b1c);
                MFMA32(P0, alo, b0);
                MFMA32(P1, alo, b1c);
                MFMA32(P0, ahi, bl0);
                MFMA32(P1, ahi, bl1);
            }
            #pragma unroll
            for (int r = 0; r < 16; ++r) {
                i1[r] = sigf(P0[r]);
                c1[r] *= sigf(P1[r]);      // c = F*c (I*G added in pass 1)
            }
        }

        // ============ L1 pass 1: gates g,o ============
        {
            f32x16 P0, P1;
            {
                float bg0 = b1[1024 + u1], bg1 = b1[1536 + u1];
                #pragma unroll
                for (int r = 0; r < 16; ++r) { P0[r] = bg0; P1[r] = bg1; }
            }
            short8 pb0, pb1;
            {
                int s0 = rev ? 35 : 0;
                const unsigned short* bb = B1p + s0 * 65536 + 2048;
                pb0 = *(const short8*)(bb);
                pb1 = *(const short8*)(bb + 1024);
            }
            #pragma unroll 1
            for (int ss = 0; ss < 36; ++ss) {
                int s = rev ? (35 - ss) : ss;
                short8 ahi, alo;
                if (s < 4) {
                    int off = s * 16 + kh * 8;
                    ahi = *(const short8*)(xh + n1 * 72 + off);
                    alo = *(const short8*)(xl + n1 * 72 + off);
                } else {
                    int off = (s - 4) * 16 + kh * 8;
                    ahi = *(const short8*)(h1hi + n1 * 520 + off);
                    alo = *(const short8*)(h1lo + n1 * 520 + off);
                }
                const unsigned short* bbc = B1p + s * 65536 + 2048;
                short8 bl0 = *(const short8*)(bbc + 512);
                short8 bl1 = *(const short8*)(bbc + 1536);
                short8 b0 = pb0, b1c = pb1;
                if (ss + 1 < 36) {
                    int s2 = rev ? (34 - ss) : (ss + 1);
                    const unsigned short* bb2 = B1p + s2 * 65536 + 2048;
                    pb0 = *(const short8*)(bb2);
                    pb1 = *(const short8*)(bb2 + 1024);
                }
                MFMA32(P0, ahi, b0);
                MFMA32(P1, ahi, b1c);
                MFMA32(P0, alo, b0);
                MFMA32(P1, alo, b1c);
                MFMA32(P0, ahi, bl0);
                MFMA32(P1, ahi, bl1);
            }
            __syncthreads();   // B: all reads of h1(t-1)/x(t) done
            #pragma unroll
            for (int r = 0; r < 16; ++r) {
                float G = tanhfast(P0[r]);
                float O = sigf(P1[r]);
                float c = c1[r] + i1[r] * G;
                c1[r] = c;
                float h = O * tanhfast(c);
                int row = (r & 3) + 8 * (r >> 2) + 4 * kh;   // verified 32x32 C-map
                unsigned short hh = f2b(h);
                h1hi[row * 520 + u1] = hh;
                h1lo[row * 520 + u1] = f2b(h - b2f(hh));
            }
        }
        __syncthreads();   // C: h1(t) visible

        // prefetch x(t+1) into the other parity buffer (overlaps L2 k-loop)
        if (t + 1 < NTIME) {
            unsigned short* xh2 = xhi + ((t + 1) & 1) * 2304;
            unsigned short* xl2 = xlo + ((t + 1) & 1) * 2304;
            #pragma unroll
            for (int e = tid; e < 2048; e += 1024) {
                int b = e >> 6, f = e & 63;
                const float* __restrict__ xp = (b < 16) ? x1 : x2;
                float v = (f < 58) ? xp[(samp0 + (b & 15)) * 1740 + f * 30 + (t + 1)] : 0.0f;
                unsigned short hi = f2b(v);
                xh2[b * 72 + f] = hi;
                xl2[b * 72 + f] = f2b(v - b2f(hi));
            }
        }

        // ============ L2: 16x16x32, k = [relu(h1) 512 | h2 128], 20 ksteps ============
        {
            f32x4 a20, a21, a22, a23;
            {
                float bg0 = b2[u2], bg1 = b2[128 + u2], bg2 = b2[256 + u2], bg3 = b2[384 + u2];
                a20 = (f32x4){bg0, bg0, bg0, bg0};
                a21 = (f32x4){bg1, bg1, bg1, bg1};
                a22 = (f32x4){bg2, bg2, bg2, bg2};
                a23 = (f32x4){bg3, bg3, bg3, bg3};
            }
            short8 pb[8];   // full 8-frag prefetch, 1 kstep ahead
            {
                int s0 = rev ? 19 : 0;
                const unsigned short* bb = B2p + s0 * 32768;
                #pragma unroll
                for (int i = 0; i < 8; ++i)
                    pb[i] = *(const short8*)(bb + (i >> 1) * 1024 + (i & 1) * 512);
            }
            #pragma unroll 1
            for (int ss = 0; ss < 20; ++ss) {
                int s = rev ? (19 - ss) : ss;
                short8 ahi, alo;
                if (s < 16) {
                    int off = s * 32 + quad * 8;
                    short8 a  = *(const short8*)(h1hi + row2 * 520 + off);
                    short8 al = *(const short8*)(h1lo + row2 * 520 + off);
                    short8 msk = a >> 15;
                    ahi = a & ~msk;
                    alo = al & ~msk;
                } else {
                    int off = (s - 16) * 32 + quad * 8;
                    ahi = *(const short8*)(h2hi + cur * 4352 + row2 * 136 + off);
                    alo = *(const short8*)(h2lo + cur * 4352 + row2 * 136 + off);
                }
                short8 cb[8];
                #pragma unroll
                for (int i = 0; i < 8; ++i) cb[i] = pb[i];
                if (ss + 1 < 20) {
                    int s2 = rev ? (18 - ss) : (ss + 1);
                    const unsigned short* bb2 = B2p + s2 * 32768;
                    #pragma unroll
                    for (int i = 0; i < 8; ++i)
                        pb[i] = *(const short8*)(bb2 + (i >> 1) * 1024 + (i & 1) * 512);
                }
                MFMA16(a20, ahi, cb[0]);
                MFMA16(a21, ahi, cb[2]);
                MFMA16(a22, ahi, cb[4]);
                MFMA16(a23, ahi, cb[6]);
                MFMA16(a20, alo, cb[0]);
                MFMA16(a21, alo, cb[2]);
                MFMA16(a22, alo, cb[4]);
                MFMA16(a23, alo, cb[6]);
                MFMA16(a20, ahi, cb[1]);
                MFMA16(a21, ahi, cb[3]);
                MFMA16(a22, ahi, cb[5]);
                MFMA16(a23, ahi, cb[7]);
            }
            #pragma unroll
            for (int r = 0; r < 4; ++r) {
                float I = sigf(a20[r]);
                float F = sigf(a21[r]);
                float G = tanhfast(a22[r]);
                float O = sigf(a23[r]);
                float c = F * c2[r] + I * G;
                c2[r] = c;
                float h = O * tanhfast(c);
                int row = mt2 * 16 + quad * 4 + r;
                unsigned short hh = f2b(h);
                h2hi[nxt * 4352 + row * 136 + u2] = hh;
                h2lo[nxt * 4352 + row * 136 + u2] = f2b(h - b2f(hh));
            }
        }
        __syncthreads();   // D: h2(t) + x(t+1) visible

        // ============ L3: 16x16x32, k = [relu(h2) 128 | h3 64], 6 ksteps (waves 0-7) ====
        if (wv < 8) {
            f32x4 a30, a31, a32, a33;
            {
                float bg0 = b3[u3], bg1 = b3[64 + u3], bg2 = b3[128 + u3], bg3 = b3[192 + u3];
                a30 = (f32x4){bg0, bg0, bg0, bg0};
                a31 = (f32x4){bg1, bg1, bg1, bg1};
                a32 = (f32x4){bg2, bg2, bg2, bg2};
                a33 = (f32x4){bg3, bg3, bg3, bg3};
            }
            short8 pb[8];
            {
                int s0 = rev ? 5 : 0;
                const unsigned short* bb = B3p + s0 * 16384;
                #pragma unroll
                for (int i = 0; i < 8; ++i)
                    pb[i] = *(const short8*)(bb + (i >> 1) * 1024 + (i & 1) * 512);
            }
            #pragma unroll 1
            for (int ss = 0; ss < 6; ++ss) {
                int s = rev ? (5 - ss) : ss;
                short8 ahi, alo;
                if (s < 4) {
                    int off = s * 32 + quad * 8;
                    short8 a  = *(const short8*)(h2hi + nxt * 4352 + row3 * 136 + off);
                    short8 al = *(const short8*)(h2lo + nxt * 4352 + row3 * 136 + off);
                    short8 msk = a >> 15;
                    ahi = a & ~msk;
                    alo = al & ~msk;
                } else {
                    int off = (s - 4) * 32 + quad * 8;
                    ahi = *(const short8*)(h3hi + cur * 2304 + row3 * 72 + off);
                    alo = *(const short8*)(h3lo + cur * 2304 + row3 * 72 + off);
                }
                short8 cb[8];
                #pragma unroll
                for (int i = 0; i < 8; ++i) cb[i] = pb[i];
                if (ss + 1 < 6) {
                    int s2 = rev ? (4 - ss) : (ss + 1);
                    const unsigned short* bb2 = B3p + s2 * 16384;
                    #pragma unroll
                    for (int i = 0; i < 8; ++i)
                        pb[i] = *(const short8*)(bb2 + (i >> 1) * 1024 + (i & 1) * 512);
                }
                MFMA16(a30, ahi, cb[0]);
                MFMA16(a31, ahi, cb[2]);
                MFMA16(a32, ahi, cb[4]);
                MFMA16(a33, ahi, cb[6]);
                MFMA16(a30, alo, cb[0]);
                MFMA16(a31, alo, cb[2]);
                MFMA16(a32, alo, cb[4]);
                MFMA16(a33, alo, cb[6]);
                MFMA16(a30, ahi, cb[1]);
                MFMA16(a31, ahi, cb[3]);
                MFMA16(a32, ahi, cb[5]);
                MFMA16(a33, ahi, cb[7]);
            }
            #pragma unroll
            for (int r = 0; r < 4; ++r) {
                float I = sigf(a30[r]);
                float F = sigf(a31[r]);
                float G = tanhfast(a32[r]);
                float O = sigf(a33[r]);
                float c = F * c3[r] + I * G;
                c3[r] = c;
                float h = O * tanhfast(c);
                int row = mt3 * 16 + quad * 4 + r;
                unsigned short hh = f2b(h);
                h3hi[nxt * 2304 + row * 72 + u3] = hh;
                h3lo[nxt * 2304 + row * 72 + u3] = f2b(h - b2f(hh));
            }
        }
        __syncthreads();   // E: h3(t) visible

        // d = |relu(h3_x1) - relu(h3_x2)| -> global
        {
            int b = tid >> 6, u = tid & 63;
            float ha = b2f(h3hi[nxt * 2304 + b * 72 + u]) + b2f(h3lo[nxt * 2304 + b * 72 + u]);
            float hb = b2f(h3hi[nxt * 2304 + (16 + b) * 72 + u]) + b2f(h3lo[nxt * 2304 + (16 + b) * 72 + u]);
            dbuf[(size_t)(samp0 + b) * 1920 + t * 64 + u] = fabsf(fmaxf(ha, 0.0f) - fmaxf(hb, 0.0f));
        }
        cur = nxt;
    }
}

// ---- FC head v2
__global__ __launch_bounds__(512) void head_v2(
    const float* __restrict__ dg,
    const float4* __restrict__ WT1, const float* __restrict__ bf1,
    const float4* __restrict__ WT2, const float* __restrict__ bf2,
    const float* __restrict__ Wf3, const float* __restrict__ bf3,
    const float* __restrict__ Wf4, const float* __restrict__ bf4,
    float* __restrict__ out)
{
    extern __shared__ float hds[];
    float* ds = hds;                  // [16][1928] during fc1
    float* a1 = hds;                  // [16][1032] overlay after fc1
    float* a2 = a1 + 16 * 1032;       // [16][520]
    float* a3 = a2 + 16 * 520;        // [16][16]

    const int tid = threadIdx.x;
    const int samp0 = blockIdx.x * 16;

    for (int e = tid; e < 16 * 480; e += 512) {
        int b = e / 480, jc = e - b * 480;
        const float* src = dg + (size_t)(samp0 + b) * 1920 + jc * 4;
        float* dst = ds + b * 1928 + jc * 4;
        dst[0] = src[0]; dst[1] = src[1]; dst[2] = src[2]; dst[3] = src[3];
    }
    __syncthreads();

    const int w = tid >> 6, lane = tid & 63;
    const int oA = w * 128 + lane, oB = oA + 64;
    float accA[16], accB[16];
    {
        float bA = (oA < 960) ? bf1[oA] : 0.0f;
        float bB = (oB < 960) ? bf1[oB] : 0.0f;
        #pragma unroll
        for (int r = 0; r < 16; ++r) { accA[r] = bA; accB[r] = bB; }
    }
    #pragma unroll 2
    for (int kc = 0; kc < 480; ++kc) {
        float4 wA = WT1[kc * 1024 + oA];
        float4 wB = WT1[kc * 1024 + oB];
        #pragma unroll
        for (int r = 0; r < 16; ++r) {
            float4 d4 = ((const float4*)(ds + r * 1928))[kc];
            accA[r] += d4.x * wA.x + d4.y * wA.y + d4.z * wA.z + d4.w * wA.w;
            accB[r] += d4.x * wB.x + d4.y * wB.y + d4.z * wB.z + d4.w * wB.w;
        }
    }
    __syncthreads();
    #pragma unroll
    for (int r = 0; r < 16; ++r) {
        a1[r * 1032 + oA] = fmaxf(accA[r], 0.0f);
        a1[r * 1032 + oB] = fmaxf(accB[r], 0.0f);
    }
    __syncthreads();

    const int o2 = tid;
    float acc2[16];
    {
        float b = (o2 < 480) ? bf2[o2] : 0.0f;
        #pragma unroll
        for (int r = 0; r < 16; ++r) acc2[r] = b;
    }
    #pragma unroll 2
    for (int kc = 0; kc < 256; ++kc) {
        float4 w4 = WT2[kc * 512 + o2];
        #pragma unroll
        for (int r = 0; r < 16; ++r) {
            float4 a4 = ((const float4*)(a1 + r * 1032))[kc];
            acc2[r] += a4.x * w4.x + a4.y * w4.y + a4.z * w4.z + a4.w * w4.w;
        }
    }
    #pragma unroll
    for (int r = 0; r < 16; ++r) a2[r * 520 + o2] = fmaxf(acc2[r], 0.0f);
    __syncthreads();

    if (tid < 256) {
        int o = tid & 15, r = tid >> 4;
        float acc = bf3[o];
        const float4* wr = (const float4*)(Wf3 + (size_t)o * 480);
        const float4* av = (const float4*)(a2 + r * 520);
        #pragma unroll 4
        for (int kc = 0; kc < 120; ++kc) {
            float4 a4 = av[kc];
            float4 w4 = wr[kc];
            acc += a4.x * w4.x + a4.y * w4.y + a4.z * w4.z + a4.w * w4.w;
        }
        a3[r * 16 + o] = fmaxf(acc, 0.0f);
    }
    __syncthreads();

    if (tid < 16) {
        float acc = bf4[0];
        #pragma unroll
        for (int k = 0; k < 16; ++k) acc += a3[tid * 16 + k] * Wf4[k];
        out[samp0 + tid] = acc;
    }
}

extern "C" void kernel_launch(void* const* d_in, const int* in_sizes, int n_in,
                              void* d_out, int out_size, void* d_ws, size_t ws_size,
                              hipStream_t stream) {
    const float* x1   = (const float*)d_in[0];
    const float* x2   = (const float*)d_in[1];
    const float* Wih1 = (const float*)d_in[2];
    const float* Whh1 = (const float*)d_in[3];
    const float* b1   = (const float*)d_in[4];
    const float* Wih2 = (const float*)d_in[5];
    const float* Whh2 = (const float*)d_in[6];
    const float* b2   = (const float*)d_in[7];
    const float* Wih3 = (const float*)d_in[8];
    const float* Whh3 = (const float*)d_in[9];
    const float* b3   = (const float*)d_in[10];
    const float* Wf1  = (const float*)d_in[11];
    const float* bf1  = (const float*)d_in[12];
    const float* Wf2  = (const float*)d_in[13];
    const float* bf2  = (const float*)d_in[14];
    const float* Wf3  = (const float*)d_in[15];
    const float* bf3  = (const float*)d_in[16];
    const float* Wf4  = (const float*)d_in[17];
    const float* bf4  = (const float*)d_in[18];

    float* wsf = (float*)d_ws;
    float* dbuf = wsf;                                         // 4096*1920 = 7,864,320 f32
    unsigned short* l1w = (unsigned short*)(wsf + 7864320);    // 36*65536  = 2,359,296 us
    unsigned short* l2w = l1w + 2359296;                       // 20*8*4096 =   655,360 us
    unsigned short* l3w = l2w + 655360;                        //  6*4*4096 =    98,304 us
    float4* WT1 = (float4*)(wsf + 9420800);                    // 480*1024 float4
    float4* WT2 = WT1 + 480 * 1024;                            // 256*512  float4
    float* out = (float*)d_out;

    prep_w32<<<(36 * 65536) / 256, 256, 0, stream>>>(Wih1, Whh1, l1w);
    prep_w16<<<(20 * 8 * 4096) / 256, 256, 0, stream>>>(Wih2, Whh2, l2w, 128, 512, 512, 128, 8, 20);
    prep_w16<<<(6 * 4 * 4096) / 256, 256, 0, stream>>>(Wih3, Whh3, l3w, 64, 128, 128, 64, 4, 6);
    pack_wt1<<<(480 * 1024) / 256, 256, 0, stream>>>(Wf1, WT1);
    pack_wt2<<<(256 * 512) / 256, 256, 0, stream>>>(Wf2, WT2);

    (void)hipFuncSetAttribute((const void*)lstm3_v2,
                              hipFuncAttributeMaxDynamicSharedMemorySize, 138240);
    lstm3_v2<<<256, 1024, 138240, stream>>>(x1, x2, l1w, l2w, l3w, b1, b2, b3, dbuf);

    (void)hipFuncSetAttribute((const void*)head_v2,
                              hipFuncAttributeMaxDynamicSharedMemorySize, 16 * 1928 * 4);
    head_v2<<<256, 512, 16 * 1928 * 4, stream>>>(dbuf, WT1, bf1, WT2, bf2,
                                                 Wf3, bf3, Wf4, bf4, out);
}